// Round 1
// baseline (199.996 us; speedup 1.0000x reference)
//
#include <hip/hip_runtime.h>
#include <stdint.h>

#define NROW 8192
#define DIM  512
#define NOUT 16
#define GAMMA 0.001f
// exp(2*gamma*c) = exp2(c * 2*gamma*log2(e))
#define EXP2S (2.0f * GAMMA * 1.44269504088896340736f)

typedef __bf16 bf16_t;
typedef bf16_t bf16x4_t __attribute__((ext_vector_type(4)));
typedef bf16_t bf16x8_t __attribute__((ext_vector_type(8)));
typedef float  floatx4_t __attribute__((ext_vector_type(4)));

// async global->LDS, 16 B/lane. LDS dest is wave-uniform base + lane*16.
__device__ __forceinline__ void async_copy16(const void* g, const void* l) {
    __builtin_amdgcn_global_load_lds(
        (__attribute__((address_space(1))) void*)(uintptr_t)g,
        (__attribute__((address_space(3))) void*)(uint32_t)(uintptr_t)l,
        16, 0, 0);
}

// ---------- prep 1: fp32 -> bf16 rows + exp(-gamma*||row||^2) factors ----------
__global__ __launch_bounds__(256) void prep_convert(
    const float* __restrict__ X, const float* __restrict__ T,
    bf16_t* __restrict__ Xb, bf16_t* __restrict__ Tb,
    float* __restrict__ xfac, float* __restrict__ yfac)
{
    const int w = threadIdx.x >> 6, lane = threadIdx.x & 63;
    const int row = blockIdx.x * 4 + w;              // 0..16383
    const float* src; bf16_t* dst; float* fac; int r;
    if (row < NROW) { src = X; dst = Xb; fac = xfac; r = row; }
    else           { src = T; dst = Tb; fac = yfac; r = row - NROW; }
    const float4* s4 = (const float4*)(src + (size_t)r * DIM);
    const float4 v0 = s4[lane];
    const float4 v1 = s4[lane + 64];
    float ss = v0.x*v0.x + v0.y*v0.y + v0.z*v0.z + v0.w*v0.w
             + v1.x*v1.x + v1.y*v1.y + v1.z*v1.z + v1.w*v1.w;
    bf16x4_t o0 = { (bf16_t)v0.x, (bf16_t)v0.y, (bf16_t)v0.z, (bf16_t)v0.w };
    bf16x4_t o1 = { (bf16_t)v1.x, (bf16_t)v1.y, (bf16_t)v1.z, (bf16_t)v1.w };
    bf16x4_t* d4 = (bf16x4_t*)(dst + (size_t)r * DIM);
    d4[lane] = o0;
    d4[lane + 64] = o1;
#pragma unroll
    for (int m = 32; m > 0; m >>= 1) ss += __shfl_xor(ss, m, 64);
    if (lane == 0) fac[r] = __expf(-GAMMA * ss);
}

// ---------- prep 2: alphaT'[o][j] = bf16( exp(-g*||y_j||^2) * alpha[j][o] ) ----------
__global__ __launch_bounds__(256) void prep_alpha(
    const float* __restrict__ alpha, const float* __restrict__ yfac,
    bf16_t* __restrict__ alphaTp)
{
    const int t = blockIdx.x * 256 + threadIdx.x;    // 131072
    const int j = t >> 4, o = t & 15;
    alphaTp[(size_t)o * NROW + j] = (bf16_t)(alpha[t] * yfac[j]);
}

// ---------- main: 128x128 bf16 MFMA GEMM + fused exp + @alpha' epilogue ----------
#define BM 128
#define BN 128
#define BK 32
#define TPT 8        // train tiles per block
#define KLD 72       // padded row stride (bf16) for the K'' transpose tile

__global__ __launch_bounds__(256) void rbf_main(
    const bf16_t* __restrict__ Xb, const bf16_t* __restrict__ Tb,
    const bf16_t* __restrict__ alphaTp, float* __restrict__ partial)
{
    // union: staging As[128][32](8KB)+Bs[128][32](8KB)  vs  Ke 4 waves x [64][72] bf16
    __shared__ __align__(16) unsigned char smem[4 * 64 * KLD * 2];
    bf16_t* As = (bf16_t*)smem;
    bf16_t* Bs = (bf16_t*)(smem + 8192);

    const int tid = threadIdx.x;
    const int w = tid >> 6, lane = tid & 63;
    const int wr = w >> 1, wc = w & 1;
    const int quad = lane >> 4, l15 = lane & 15;

    const int rb = blockIdx.y;                       // 0..63
    const int chunk = blockIdx.x;                    // 0..7
    const int row0 = rb * BM;

    // global_load_lds slot: s = tid (issue 1), tid+256 (issue 2); row = s>>2, 16B col = s&3
    const int s_row = tid >> 2;
    const int s_colb = (tid & 3) * 16;
    const char* gA = (const char*)(Xb + (size_t)(row0 + s_row) * DIM) + s_colb;
    const unsigned ldsW = (unsigned)(w << 10);       // wave-uniform LDS base

    const floatx4_t vzero = {0.f, 0.f, 0.f, 0.f};
    floatx4_t oacc[4];
#pragma unroll
    for (int i = 0; i < 4; ++i) oacc[i] = vzero;

    bf16_t* kw = (bf16_t*)smem + w * (64 * KLD);     // this wave's K'' region

    for (int t = 0; t < TPT; ++t) {
        const int cb = chunk * (TPT * BN) + t * BN;
        const char* gB = (const char*)(Tb + (size_t)(cb + s_row) * DIM) + s_colb;

        floatx4_t acc[4][4];
#pragma unroll
        for (int i = 0; i < 4; ++i)
#pragma unroll
            for (int j = 0; j < 4; ++j) acc[i][j] = vzero;

        for (int kb = 0; kb < DIM * 2; kb += BK * 2) {   // byte offset along K
            __syncthreads();                             // prev LDS reads done
            async_copy16(gA + kb,           smem + ldsW);
            async_copy16(gA + 65536 + kb,   smem + 4096 + ldsW);
            async_copy16(gB + kb,           smem + 8192 + ldsW);
            async_copy16(gB + 65536 + kb,   smem + 12288 + ldsW);
            __syncthreads();                             // drains vmcnt: loads landed

            bf16x8_t af[4], bfv[4];
#pragma unroll
            for (int i = 0; i < 4; ++i) {
                af[i]  = *(const bf16x8_t*)(As + (wr * 64 + i * 16 + l15) * BK + quad * 8);
                bfv[i] = *(const bf16x8_t*)(Bs + (wc * 64 + i * 16 + l15) * BK + quad * 8);
            }
#pragma unroll
            for (int mi = 0; mi < 4; ++mi)
#pragma unroll
                for (int ni = 0; ni < 4; ++ni)
                    acc[mi][ni] = __builtin_amdgcn_mfma_f32_16x16x32_bf16(
                        af[mi], bfv[ni], acc[mi][ni], 0, 0, 0);
        }

        __syncthreads();   // all frag reads of As/Bs done before overwrite with Ke
        // K'' = exp(2*gamma*cross), bf16, into padded per-wave LDS tile
        // C layout: row = quad*4 + reg, col = l15 (within each 16x16 tile)
#pragma unroll
        for (int mi = 0; mi < 4; ++mi)
#pragma unroll
            for (int ni = 0; ni < 4; ++ni) {
                const int col = ni * 16 + l15;
#pragma unroll
                for (int r = 0; r < 4; ++r) {
                    float e = __builtin_amdgcn_exp2f(acc[mi][ni][r] * EXP2S);
                    kw[(mi * 16 + quad * 4 + r) * KLD + col] = (bf16_t)e;
                }
            }
        __syncthreads();

        // epilogue GEMM: oacc[mi] += K''[16 rows x 64 cols] @ alpha'[64 x 16]
#pragma unroll
        for (int ks = 0; ks < 2; ++ks) {
            const bf16x8_t bv = *(const bf16x8_t*)(alphaTp + (size_t)l15 * NROW
                                                   + cb + wc * 64 + ks * 32 + quad * 8);
#pragma unroll
            for (int mi = 0; mi < 4; ++mi) {
                const bf16x8_t av = *(const bf16x8_t*)(kw + (mi * 16 + l15) * KLD
                                                       + ks * 32 + quad * 8);
                oacc[mi] = __builtin_amdgcn_mfma_f32_16x16x32_bf16(av, bv, oacc[mi], 0, 0, 0);
            }
        }
        // next t: leading __syncthreads() protects Ke reads vs restaging
    }

    // partial[chunk*2+wc][row][o]
    float* pb = partial + (size_t)(chunk * 2 + wc) * (NROW * NOUT);
#pragma unroll
    for (int mi = 0; mi < 4; ++mi) {
        const int grow = row0 + wr * 64 + mi * 16 + quad * 4;
#pragma unroll
        for (int r = 0; r < 4; ++r)
            pb[(size_t)(grow + r) * NOUT + l15] = oacc[mi][r];
    }
}

// ---------- reducer: out = xfac[row] * sum_pc partial ----------
__global__ __launch_bounds__(256) void reduce_out(
    const float* __restrict__ partial, const float* __restrict__ xfac,
    float* __restrict__ out)
{
    const int t = blockIdx.x * 256 + threadIdx.x;    // 131072
    float s = 0.f;
#pragma unroll
    for (int p = 0; p < 16; ++p) s += partial[(size_t)p * (NROW * NOUT) + t];
    out[t] = s * xfac[t >> 4];
}

extern "C" void kernel_launch(void* const* d_in, const int* in_sizes, int n_in,
                              void* d_out, int out_size, void* d_ws, size_t ws_size,
                              hipStream_t stream) {
    (void)in_sizes; (void)n_in; (void)out_size; (void)ws_size;
    const float* X     = (const float*)d_in[0];
    const float* T     = (const float*)d_in[1];
    const float* alpha = (const float*)d_in[2];

    char* ws = (char*)d_ws;
    bf16_t* Xb      = (bf16_t*)ws;                                   // 8 MB
    bf16_t* Tb      = (bf16_t*)(ws + (8u << 20));                    // 8 MB
    float*  xfac    = (float*)(ws + (16u << 20));                    // 32 KB
    float*  yfac    = (float*)(ws + (16u << 20) + (32u << 10));      // 32 KB
    bf16_t* alphaTp = (bf16_t*)(ws + (16u << 20) + (64u << 10));     // 256 KB
    float*  partial = (float*)(ws + (17u << 20));                    // 8 MB (16 slices)
    float*  out     = (float*)d_out;

    prep_convert<<<4096, 256, 0, stream>>>(X, T, Xb, Tb, xfac, yfac);
    prep_alpha<<<512, 256, 0, stream>>>(alpha, yfac, alphaTp);
    dim3 grid(8, 64);
    rbf_main<<<grid, 256, 0, stream>>>(Xb, Tb, alphaTp, partial);
    reduce_out<<<512, 256, 0, stream>>>(partial, xfac, out);
}